// Round 3
// baseline (272.617 us; speedup 1.0000x reference)
//
#include <hip/hip_runtime.h>

#define H_ 1024
#define W_ 1024
#define B_ 4
#define CIN 16
#define COUT 16
#define TH 8
#define TW 32
#define NT 8          // vertical tiles per block
#define ROWS 10       // TH+2
#define COLS 34       // TW+2
#define COLS_P 36     // padded col stride (+2*half applied in toff)

#define LRELU 0.2f
#define GAIN_ 1.4142135623730951f
#define EPS_ 1e-8f

typedef __attribute__((ext_vector_type(8))) short bf16x8;
typedef __attribute__((ext_vector_type(4))) float f32x4;

static __device__ __forceinline__ unsigned short f32_to_bf16(float f) {
    unsigned int u = __float_as_uint(f);
    unsigned int r = u + 0x7FFF + ((u >> 16) & 1);   // RNE
    return (unsigned short)(r >> 16);
}

// ---------------- setup 1: s[b,i] = w @ (fcw.T * 512^-0.5) + bias; copy w to out ----
__global__ __launch_bounds__(256) void k_setup1(
    const float* __restrict__ w, const float* __restrict__ fcw,
    const float* __restrict__ fcb, float* __restrict__ s_out,
    float* __restrict__ w_copy_out)
{
    __shared__ float part[256];
    const int tid = threadIdx.x;
    const int bi = tid >> 2;   // 0..63 -> (b,i)
    const int q  = tid & 3;
    const int b = bi >> 4, i = bi & 15;
    const float* wr = w + b * 512 + q * 128;
    const float* fr = fcw + i * 512 + q * 128;
    float acc = 0.f;
    #pragma unroll 8
    for (int k = 0; k < 128; ++k) acc += wr[k] * fr[k];
    part[tid] = acc;
    __syncthreads();
    if (tid < 64) {
        float v = part[tid*4] + part[tid*4+1] + part[tid*4+2] + part[tid*4+3];
        s_out[tid] = v * 0.04419417382415922f /* 512^-0.5 */ + fcb[tid & 15];
    }
    for (int e = tid; e < B_ * 512; e += 256) w_copy_out[e] = w[e];
}

// ---------------- setup 2: d[b,o], W_eff -> pre-swizzled bf16 A-fragments ----------
// afrag layout: [b][t=0..4][lane=0..63][j=0..7], A[o=lane&15][k=g*8+j],
// k -> (tap = 2t + (g>>1), i = (g&1)*8 + j); tap 9 zeroed.
__global__ __launch_bounds__(256) void k_setup2(
    const float* __restrict__ s_in, const float* __restrict__ convw,
    unsigned short* __restrict__ afrag)
{
    const int b = blockIdx.x;
    const int tid = threadIdx.x;
    __shared__ float s_sh[16];
    __shared__ float d_sh[16];
    __shared__ float wc_sh[COUT * CIN * 9];
    __shared__ float part[256];

    if (tid < 16) s_sh[tid] = s_in[b * 16 + tid];
    for (int e = tid; e < COUT * CIN * 9; e += 256)
        wc_sh[e] = convw[e] * (1.0f / 12.0f);   // (16*9)^-0.5
    __syncthreads();

    const int o = tid >> 4, i = tid & 15;
    const float si = s_sh[i];
    float acc = 0.f;
    #pragma unroll
    for (int tap = 0; tap < 9; ++tap) {
        float v = wc_sh[(o * 16 + i) * 9 + tap] * si;
        acc += v * v;
    }
    part[tid] = acc;
    __syncthreads();
    if (tid < 16) {
        float sum = EPS_;
        #pragma unroll
        for (int j = 0; j < 16; ++j) sum += part[tid * 16 + j];
        d_sh[tid] = rsqrtf(sum);
    }
    __syncthreads();

    for (int e = tid; e < 5 * 64 * 8; e += 256) {
        int t = e >> 9;
        int lane = (e >> 3) & 63;
        int j = e & 7;
        int oo = lane & 15, g = lane >> 4;
        int ii = (g & 1) * 8 + j;
        int tap = 2 * t + (g >> 1);
        float v = 0.f;
        if (tap < 9) v = wc_sh[(oo * 16 + ii) * 9 + tap] * s_sh[ii] * d_sh[oo];
        afrag[(size_t)b * (5 * 64 * 8) + e] = f32_to_bf16(v);
    }
}

// ---------------- main conv: multi-tile pipelined implicit GEMM ---------------------
// Each block: TW=32 cols x NT*TH=64 rows, double-buffered LDS, async-STAGE split:
//   load(t+1)->regs ; MFMA(t) ; ds_write(t+1) ; stores(t) ; barrier
__global__ __launch_bounds__(256, 4) void k_conv(
    const float* __restrict__ x, const float* __restrict__ noise,
    const float* __restrict__ conv_bias, const float* __restrict__ sn_ptr,
    const unsigned short* __restrict__ afrag, float* __restrict__ y)
{
    __shared__ unsigned short tile[2 * 2 * ROWS * COLS_P * 8]; // 23040 B

    const int tid = threadIdx.x;
    const int bt = blockIdx.z;
    const int h0 = blockIdx.y * (TH * NT);
    const int w0 = blockIdx.x * TW;
    const float sn = sn_ptr[0];
    const float* xb = x + (size_t)bt * CIN * H_ * W_;
    float* yb = y + (size_t)bt * COUT * H_ * W_;
    const float* nb = noise + (size_t)bt * H_ * W_;

    const int lane  = tid & 63;
    const int wid   = tid >> 6;
    const int p     = lane & 15;
    const int g     = lane >> 4;
    const int ghalf = g >> 1;
    const int chalf = g & 1;

    // staging roles
    const bool is_int  = (tid < 160);
    const bool is_edge = (tid >= 160) && (tid < 200);
    const int s_row = is_int ? (tid >> 4) : ((tid - 160) >> 2);
    const int s_sub = tid & 15;
    const int s_hh  = is_int ? (s_sub >> 3) : ((tid - 160) & 1);
    const int s_cg  = s_sub & 7;
    const int s_side = ((tid - 160) >> 1) & 1;

    // LDS offset in u16 units
    auto toff = [&](int buf, int half, int row, int col) -> int {
        return (((buf * 2 + half) * ROWS + row) * COLS_P + col + 2 * half) * 8;
    };

    float4 v[8];
    float  ev[8];

    auto stage_load = [&](int t) {
        const int gh0 = h0 + TH * t - 1;
        if (is_int) {
            const int gh = gh0 + s_row;
            const bool ok = (gh >= 0) && (gh < H_);
            const float* base = xb + ((size_t)(8 * s_hh) * H_ + gh) * W_ + (w0 + 4 * s_cg);
            #pragma unroll
            for (int c = 0; c < 8; ++c) {
                v[c] = make_float4(0.f, 0.f, 0.f, 0.f);
                if (ok) v[c] = *reinterpret_cast<const float4*>(base + (size_t)c * H_ * W_);
            }
        } else if (is_edge) {
            const int gh = gh0 + s_row;
            const int gw = w0 - 1 + s_side * (COLS - 1);
            const bool ok = (gh >= 0) && (gh < H_) && (gw >= 0) && (gw < W_);
            #pragma unroll
            for (int c = 0; c < 8; ++c)
                ev[c] = ok ? xb[((size_t)(8 * s_hh + c) * H_ + gh) * W_ + gw] : 0.f;
        }
    };

    auto stage_write = [&](int buf) {
        if (is_int) {
            #pragma unroll
            for (int px = 0; px < 4; ++px) {
                bf16x8 pk;
                #pragma unroll
                for (int c = 0; c < 8; ++c) {
                    float f = px == 0 ? v[c].x : px == 1 ? v[c].y : px == 2 ? v[c].z : v[c].w;
                    pk[c] = (short)f32_to_bf16(f);
                }
                *reinterpret_cast<bf16x8*>(&tile[toff(buf, s_hh, s_row, 1 + 4 * s_cg + px)]) = pk;
            }
        } else if (is_edge) {
            bf16x8 pk;
            #pragma unroll
            for (int c = 0; c < 8; ++c) pk[c] = (short)f32_to_bf16(ev[c]);
            *reinterpret_cast<bf16x8*>(&tile[toff(buf, s_hh, s_row, s_side * (COLS - 1))]) = pk;
        }
    };

    // preload A-fragments and bias
    bf16x8 a[5];
    {
        const bf16x8* ap = reinterpret_cast<const bf16x8*>(afrag + (size_t)bt * 5 * 64 * 8);
        #pragma unroll
        for (int t = 0; t < 5; ++t) a[t] = ap[t * 64 + lane];
    }
    float bias_j[4];
    #pragma unroll
    for (int j = 0; j < 4; ++j) bias_j[j] = conv_bias[g * 4 + j];

    int lroff[5], lcoff[5];
    #pragma unroll
    for (int t = 0; t < 5; ++t) {
        int tap = 2 * t + ghalf;
        if (tap > 8) tap = 8;        // padded slot; A is zero there
        lroff[t] = tap / 3;
        lcoff[t] = tap % 3;
    }

    auto compute = [&](int t, int buf) {
        #pragma unroll
        for (int rr = 0; rr < 2; ++rr) {
            const int oh = wid * 2 + rr;
            #pragma unroll
            for (int gc = 0; gc < 2; ++gc) {
                const int ow = gc * 16;
                f32x4 acc = {0.f, 0.f, 0.f, 0.f};
                #pragma unroll
                for (int tt = 0; tt < 5; ++tt) {
                    const bf16x8 bv = *reinterpret_cast<const bf16x8*>(
                        &tile[toff(buf, chalf, oh + lroff[tt], ow + p + lcoff[tt])]);
                    acc = __builtin_amdgcn_mfma_f32_16x16x32_bf16(a[tt], bv, acc, 0, 0, 0);
                }
                const int gh = h0 + TH * t + oh;
                const int gw = w0 + ow + p;
                const float noi = nb[(size_t)gh * W_ + gw] * sn;
                #pragma unroll
                for (int j = 0; j < 4; ++j) {
                    float vv = acc[j] + bias_j[j] + noi;
                    vv = (vv >= 0.f) ? vv : (LRELU * vv);
                    yb[((size_t)(g * 4 + j) * H_ + gh) * W_ + gw] = vv * GAIN_;
                }
            }
        }
    };

    // ---- pipeline ----
    stage_load(0);
    stage_write(0);
    for (int t = 0; t < NT - 1; ++t) {
        __syncthreads();
        stage_load(t + 1);
        compute(t, t & 1);
        stage_write((t + 1) & 1);
    }
    __syncthreads();
    compute(NT - 1, (NT - 1) & 1);
}

extern "C" void kernel_launch(void* const* d_in, const int* in_sizes, int n_in,
                              void* d_out, int out_size, void* d_ws, size_t ws_size,
                              hipStream_t stream)
{
    const float* w     = (const float*)d_in[0];
    const float* x     = (const float*)d_in[1];
    const float* noise = (const float*)d_in[2];
    const float* fcw   = (const float*)d_in[3];
    const float* fcb   = (const float*)d_in[4];
    const float* convw = (const float*)d_in[5];
    const float* convb = (const float*)d_in[6];
    const float* sn    = (const float*)d_in[7];

    float* out = (float*)d_out;
    float* ws_s = (float*)d_ws;                                        // 64 f32
    unsigned short* ws_afrag = (unsigned short*)((char*)d_ws + 256);   // 10240 u16

    k_setup1<<<1, 256, 0, stream>>>(w, fcw, fcb, ws_s, out);
    k_setup2<<<B_, 256, 0, stream>>>(ws_s, convw, ws_afrag);
    dim3 grid(W_ / TW, H_ / (TH * NT), B_);
    k_conv<<<grid, 256, 0, stream>>>(x, noise, convb, sn, ws_afrag, out + 2048);
}

// Round 4
// 197.548 us; speedup vs baseline: 1.3800x; 1.3800x over previous
//
#include <hip/hip_runtime.h>

#define H_ 1024
#define W_ 1024
#define B_ 4
#define CIN 16
#define COUT 16
#define TH 8
#define TW 64
#define NT 4          // vertical tiles per block
#define ROWS 10       // TH+2
#define COLS 66       // TW+2

#define LRELU 0.2f
#define GAIN_ 1.4142135623730951f
#define EPS_ 1e-8f

typedef __attribute__((ext_vector_type(8))) short bf16x8;
typedef __attribute__((ext_vector_type(4))) float f32x4;

static __device__ __forceinline__ unsigned short f32_to_bf16(float f) {
    unsigned int u = __float_as_uint(f);
    unsigned int r = u + 0x7FFF + ((u >> 16) & 1);   // RNE
    return (unsigned short)(r >> 16);
}

static __device__ __forceinline__ float f4c(const float4& v, int px) {
    return px == 0 ? v.x : px == 1 ? v.y : px == 2 ? v.z : v.w;
}

// ---------------- setup 1: s[b,i] = w @ (fcw.T * 512^-0.5) + bias; copy w to out ----
__global__ __launch_bounds__(256) void k_setup1(
    const float* __restrict__ w, const float* __restrict__ fcw,
    const float* __restrict__ fcb, float* __restrict__ s_out,
    float* __restrict__ w_copy_out)
{
    __shared__ float part[256];
    const int tid = threadIdx.x;
    const int bi = tid >> 2;   // 0..63 -> (b,i)
    const int q  = tid & 3;
    const int b = bi >> 4, i = bi & 15;
    const float* wr = w + b * 512 + q * 128;
    const float* fr = fcw + i * 512 + q * 128;
    float acc = 0.f;
    #pragma unroll 8
    for (int k = 0; k < 128; ++k) acc += wr[k] * fr[k];
    part[tid] = acc;
    __syncthreads();
    if (tid < 64) {
        float v = part[tid*4] + part[tid*4+1] + part[tid*4+2] + part[tid*4+3];
        s_out[tid] = v * 0.04419417382415922f /* 512^-0.5 */ + fcb[tid & 15];
    }
    for (int e = tid; e < B_ * 512; e += 256) w_copy_out[e] = w[e];
}

// ---------------- setup 2: d[b,o], W_eff -> pre-swizzled bf16 A-fragments ----------
// afrag layout: [b][t=0..4][lane=0..63][j=0..7], A[o=lane&15][k=g*8+j],
// k -> (tap = 2t + (g>>1), i = (g&1)*8 + j); tap 9 zeroed.
__global__ __launch_bounds__(256) void k_setup2(
    const float* __restrict__ s_in, const float* __restrict__ convw,
    unsigned short* __restrict__ afrag)
{
    const int b = blockIdx.x;
    const int tid = threadIdx.x;
    __shared__ float s_sh[16];
    __shared__ float d_sh[16];
    __shared__ float wc_sh[COUT * CIN * 9];
    __shared__ float part[256];

    if (tid < 16) s_sh[tid] = s_in[b * 16 + tid];
    for (int e = tid; e < COUT * CIN * 9; e += 256)
        wc_sh[e] = convw[e] * (1.0f / 12.0f);   // (16*9)^-0.5
    __syncthreads();

    const int o = tid >> 4, i = tid & 15;
    const float si = s_sh[i];
    float acc = 0.f;
    #pragma unroll
    for (int tap = 0; tap < 9; ++tap) {
        float v = wc_sh[(o * 16 + i) * 9 + tap] * si;
        acc += v * v;
    }
    part[tid] = acc;
    __syncthreads();
    if (tid < 16) {
        float sum = EPS_;
        #pragma unroll
        for (int j = 0; j < 16; ++j) sum += part[tid * 16 + j];
        d_sh[tid] = rsqrtf(sum);
    }
    __syncthreads();

    for (int e = tid; e < 5 * 64 * 8; e += 256) {
        int t = e >> 9;
        int lane = (e >> 3) & 63;
        int j = e & 7;
        int oo = lane & 15, g = lane >> 4;
        int ii = (g & 1) * 8 + j;
        int tap = 2 * t + (g >> 1);
        float v = 0.f;
        if (tap < 9) v = wc_sh[(oo * 16 + ii) * 9 + tap] * s_sh[ii] * d_sh[oo];
        afrag[(size_t)b * (5 * 64 * 8) + e] = f32_to_bf16(v);
    }
}

// ---------------- main conv: multi-tile pipelined implicit GEMM, TW=64 --------------
// Per block: 64 cols x NT*8 rows. Double-buffered LDS; per tile step:
//   barrier ; load(t+1)->regs ; MFMA+epilogue(t) ; ds_write(t+1)
// Staging units: 320 interior (all tids + tid<64 double duty) + 40 edge (tid 64..103).
__global__ __launch_bounds__(256, 3) void k_conv(
    const float* __restrict__ x, const float* __restrict__ noise,
    const float* __restrict__ conv_bias, const float* __restrict__ sn_ptr,
    const unsigned short* __restrict__ afrag, float* __restrict__ y)
{
    __shared__ unsigned short tile[2][2][ROWS][COLS][8]; // 42240 B

    const int tid = threadIdx.x;
    const int bt = blockIdx.z;
    const int h0 = blockIdx.y * (TH * NT);
    const int w0 = blockIdx.x * TW;
    const float sn = sn_ptr[0];
    const float* xb = x + (size_t)bt * CIN * H_ * W_;
    float* yb = y + (size_t)bt * COUT * H_ * W_;
    const float* nb = noise + (size_t)bt * H_ * W_;

    const int lane  = tid & 63;
    const int wid   = tid >> 6;
    const int p     = lane & 15;
    const int g     = lane >> 4;
    const int ghalf = g >> 1;
    const int chalf = g & 1;

    // staging decomposition
    const int rowA = tid >> 5, subA = tid & 31, hhA = subA >> 4, cgA = subA & 15;
    const int rowB = 8 + (tid >> 5);          // valid for tid<64 -> rows 8,9
    const bool hasB = (tid < 64);
    const bool hasE = (tid >= 64) && (tid < 104);
    const int e_  = tid - 64;
    const int rowE = e_ >> 2, sideE = (e_ >> 1) & 1, hhE = e_ & 1;

    float4 vA[8], vB[8];
    float  ev[8];

    auto stage_load = [&](int t) {
        const int gh0 = h0 + TH * t - 1;
        {
            const int gh = gh0 + rowA;
            const bool ok = (gh >= 0) && (gh < H_);
            const float* base = xb + ((size_t)(8 * hhA) * H_ + gh) * W_ + (w0 + 4 * cgA);
            #pragma unroll
            for (int c = 0; c < 8; ++c) {
                vA[c] = make_float4(0.f, 0.f, 0.f, 0.f);
                if (ok) vA[c] = *reinterpret_cast<const float4*>(base + (size_t)c * H_ * W_);
            }
        }
        if (hasB) {
            const int gh = gh0 + rowB;
            const bool ok = (gh >= 0) && (gh < H_);
            const float* base = xb + ((size_t)(8 * hhA) * H_ + gh) * W_ + (w0 + 4 * cgA);
            #pragma unroll
            for (int c = 0; c < 8; ++c) {
                vB[c] = make_float4(0.f, 0.f, 0.f, 0.f);
                if (ok) vB[c] = *reinterpret_cast<const float4*>(base + (size_t)c * H_ * W_);
            }
        } else if (hasE) {
            const int gh = gh0 + rowE;
            const int gw = w0 - 1 + sideE * (COLS - 1);
            const bool ok = (gh >= 0) && (gh < H_) && (gw >= 0) && (gw < W_);
            #pragma unroll
            for (int c = 0; c < 8; ++c)
                ev[c] = ok ? xb[((size_t)(8 * hhE + c) * H_ + gh) * W_ + gw] : 0.f;
        }
    };

    auto stage_write = [&](int buf) {
        #pragma unroll
        for (int px = 0; px < 4; ++px) {
            bf16x8 pk;
            #pragma unroll
            for (int c = 0; c < 8; ++c) pk[c] = (short)f32_to_bf16(f4c(vA[c], px));
            *reinterpret_cast<bf16x8*>(&tile[buf][hhA][rowA][1 + 4 * cgA + px][0]) = pk;
        }
        if (hasB) {
            #pragma unroll
            for (int px = 0; px < 4; ++px) {
                bf16x8 pk;
                #pragma unroll
                for (int c = 0; c < 8; ++c) pk[c] = (short)f32_to_bf16(f4c(vB[c], px));
                *reinterpret_cast<bf16x8*>(&tile[buf][hhA][rowB][1 + 4 * cgA + px][0]) = pk;
            }
        } else if (hasE) {
            bf16x8 pk;
            #pragma unroll
            for (int c = 0; c < 8; ++c) pk[c] = (short)f32_to_bf16(ev[c]);
            *reinterpret_cast<bf16x8*>(&tile[buf][hhE][rowE][sideE * (COLS - 1)][0]) = pk;
        }
    };

    // preload A-fragments and bias
    bf16x8 a[5];
    {
        const bf16x8* ap = reinterpret_cast<const bf16x8*>(afrag + (size_t)bt * 5 * 64 * 8);
        #pragma unroll
        for (int t = 0; t < 5; ++t) a[t] = ap[t * 64 + lane];
    }
    float bias_j[4];
    #pragma unroll
    for (int j = 0; j < 4; ++j) bias_j[j] = conv_bias[g * 4 + j];

    int lroff[5], lcoff[5];
    #pragma unroll
    for (int t = 0; t < 5; ++t) {
        int tap = 2 * t + ghalf;
        if (tap > 8) tap = 8;        // padded slot; A is zero there
        lroff[t] = tap / 3;
        lcoff[t] = tap % 3;
    }

    auto compute = [&](int t, int buf) {
        #pragma unroll
        for (int rr = 0; rr < 2; ++rr) {
            const int oh = wid * 2 + rr;
            #pragma unroll
            for (int gc = 0; gc < 4; ++gc) {
                const int ow = gc * 16;
                f32x4 acc = {0.f, 0.f, 0.f, 0.f};
                #pragma unroll
                for (int tt = 0; tt < 5; ++tt) {
                    const bf16x8 bv = *reinterpret_cast<const bf16x8*>(
                        &tile[buf][chalf][oh + lroff[tt]][ow + p + lcoff[tt]][0]);
                    acc = __builtin_amdgcn_mfma_f32_16x16x32_bf16(a[tt], bv, acc, 0, 0, 0);
                }
                const int gh = h0 + TH * t + oh;
                const int gw = w0 + ow + p;
                const float noi = nb[(size_t)gh * W_ + gw] * sn;
                #pragma unroll
                for (int j = 0; j < 4; ++j) {
                    float vv = acc[j] + bias_j[j] + noi;
                    vv = (vv >= 0.f) ? vv : (LRELU * vv);
                    yb[((size_t)(g * 4 + j) * H_ + gh) * W_ + gw] = vv * GAIN_;
                }
            }
        }
    };

    // ---- pipeline ----
    stage_load(0);
    stage_write(0);
    for (int t = 0; t < NT - 1; ++t) {
        __syncthreads();
        stage_load(t + 1);
        compute(t, t & 1);
        stage_write((t + 1) & 1);
    }
    __syncthreads();
    compute(NT - 1, (NT - 1) & 1);
}

extern "C" void kernel_launch(void* const* d_in, const int* in_sizes, int n_in,
                              void* d_out, int out_size, void* d_ws, size_t ws_size,
                              hipStream_t stream)
{
    const float* w     = (const float*)d_in[0];
    const float* x     = (const float*)d_in[1];
    const float* noise = (const float*)d_in[2];
    const float* fcw   = (const float*)d_in[3];
    const float* fcb   = (const float*)d_in[4];
    const float* convw = (const float*)d_in[5];
    const float* convb = (const float*)d_in[6];
    const float* sn    = (const float*)d_in[7];

    float* out = (float*)d_out;
    float* ws_s = (float*)d_ws;                                        // 64 f32
    unsigned short* ws_afrag = (unsigned short*)((char*)d_ws + 256);   // 10240 u16

    k_setup1<<<1, 256, 0, stream>>>(w, fcw, fcb, ws_s, out);
    k_setup2<<<B_, 256, 0, stream>>>(ws_s, convw, ws_afrag);
    dim3 grid(W_ / TW, H_ / (TH * NT), B_);
    k_conv<<<grid, 256, 0, stream>>>(x, noise, convb, sn, ws_afrag, out + 2048);
}